// Round 7
// baseline (259.495 us; speedup 1.0000x reference)
//
#include <hip/hip_runtime.h>

#define EPS 1e-3f

// ---------------- workspace layout (float slots) ----------------
// bytes 0..28671 : bf16 fused weights in FRAG-MAJOR layout (init_k block 0)
//   w1frag  u16[4 frag][64 lane][8]   @ u16 0     (4KB)   frag=mt
//   w2afrag u16[8 frag][64 lane][8]   @ u16 2048  (8KB)   frag=mt
//   w2bfrag u16[16 frag][64 lane][8]  @ u16 6144  (16KB)  frag=mt*4+ks
// element j of frag f, lane(c,g): weight[row = mt*16+c][k = (ks*32)+g*8+j]
#define OFF_T2B    7168              // f32[64]
#define OFF_MPP    7232              // f32[64][64] max-pool partials (memset)
#define OFF_CNT    11328             // i32[20016]  histogram (memset w/ mpp)
#define OFF_OFFS   31344             // i32[S+1] CSR offsets
#define OFF_CUR    51360             // i32[S]   scatter cursors
#define OFF_INPS   71424             // bf16[N][16] sorted inputs (32B/pt)

typedef short short8 __attribute__((ext_vector_type(8)));
typedef float f32x4 __attribute__((ext_vector_type(4)));

union U4 { unsigned u[4]; short8 s8; uint4 u4; };

__device__ inline unsigned short f2bf(float f) {           // RNE f32->bf16
    unsigned u = __float_as_uint(f);
    return (unsigned short)((u + 0x7FFFu + ((u >> 16) & 1u)) >> 16);
}

// block 0: fuse BN into bf16 weights (frag-major); blocks 1..: histogram
__global__ __launch_bounds__(256) void init_k(
    const float* __restrict__ W1,
    const float* __restrict__ g1, const float* __restrict__ b1,
    const float* __restrict__ m1, const float* __restrict__ v1,
    const float* __restrict__ W2a,
    const float* __restrict__ g2a, const float* __restrict__ b2a,
    const float* __restrict__ m2a, const float* __restrict__ v2a,
    const float* __restrict__ W2b,
    const float* __restrict__ g2b, const float* __restrict__ b2b,
    const float* __restrict__ m2b, const float* __restrict__ v2b,
    unsigned short* __restrict__ wsu, float* __restrict__ wsf,
    const int* __restrict__ unq, int* __restrict__ cnt, int N)
{
    const int t = threadIdx.x;
    if (blockIdx.x == 0) {
        for (int i = t; i < 2048; i += 256) {           // w1frag
            int mt = i >> 9, lane = (i >> 3) & 63, j = i & 7;
            int c = lane & 15, g = lane >> 4;
            int k = g * 8 + j, ch = mt * 16 + c;
            float s = g1[ch] * rsqrtf(v1[ch] + EPS);
            float val = (k < 16) ? W1[k * 64 + ch] * s
                      : (k == 16 ? b1[ch] - m1[ch] * s : 0.f);
            wsu[i] = f2bf(val);
        }
        for (int i = t; i < 4096; i += 256) {           // w2afrag
            int mt = i >> 9, lane = (i >> 3) & 63, j = i & 7;
            int c = lane & 15, g = lane >> 4;
            int k = g * 8 + j, ch = mt * 16 + c;
            float s = g2a[ch] * rsqrtf(v2a[ch] + EPS);
            float val = (k < 16) ? W2a[k * 128 + ch] * s
                      : (k == 16 ? b2a[ch] - m2a[ch] * s : 0.f);
            wsu[2048 + i] = f2bf(val);
        }
        for (int i = t; i < 8192; i += 256) {           // w2bfrag
            int f = i >> 9, lane = (i >> 3) & 63, j = i & 7;
            int mt = f >> 2, ks = f & 3;
            int c = lane & 15, g = lane >> 4;
            int k = ks * 32 + g * 8 + j, ch = mt * 16 + c;
            float s = g2b[ch] * rsqrtf(v2b[ch] + EPS);
            wsu[6144 + i] = f2bf(W2b[k * 64 + ch] * s);
        }
        if (t < 64) {
            float s = g2b[t] * rsqrtf(v2b[t] + EPS);
            wsf[OFF_T2B + t] = b2b[t] - m2b[t] * s;
        }
    } else {
        const int i = (blockIdx.x - 1) * 256 + t;
        if (i < N) atomicAdd(&cnt[unq[i]], 1);
    }
}

// serial-per-thread two-pass scan
__global__ __launch_bounds__(1024) void scan_k(
    const int* __restrict__ cnt, int* __restrict__ offs,
    int* __restrict__ cur, int S)
{
    __shared__ int tot[1024];
    const int t = threadIdx.x;
    const int E = (S + 1023) >> 10;
    const int i0 = t * E;
    int run = 0;
    for (int j = 0; j < E; ++j) {
        const int i = i0 + j;
        run += (i < S) ? cnt[i] : 0;
    }
    tot[t] = run;
    __syncthreads();
    for (int d = 1; d < 1024; d <<= 1) {
        int x = (t >= d) ? tot[t - d] : 0;
        __syncthreads();
        tot[t] += x;
        __syncthreads();
    }
    int base = (t == 0) ? 0 : tot[t - 1];
    for (int j = 0; j < E; ++j) {
        const int i = i0 + j;
        if (i < S) {
            offs[i] = base;
            cur[i]  = base;
            base += cnt[i];
        }
    }
    if (t == 1023) offs[S] = tot[1023];
}

// Fused scatter + branch2 + global max-pool. All weight reads are
// conflict-free frag-major ds_read_b128 ((f*64+lane)*16). Scatter atomics
// batched once per wave (1/lane) so latency hides under the tile loop.
__global__ __launch_bounds__(512, 4) void scatbr2_k(
    const float* __restrict__ inputs,
    const int*   __restrict__ unq,
    int*         __restrict__ cur,
    uint4*       __restrict__ inpS,
    const uint4* __restrict__ wsw,
    const float* __restrict__ wsf,
    float* __restrict__ mpp,
    int N)
{
    __shared__ __align__(16) char wlds[24576];   // w2afrag 8KB @0, w2bfrag 16KB @8192
    __shared__ float t2bs[64];
    __shared__ float mpb[64];
    __shared__ __align__(16) char scrs[8][4096]; // per-wave h staging (bf16)

    const int tid = threadIdx.x;
    {
        #pragma unroll
        for (int u = 0; u < 3; ++u)              // 1536 uint4 = 24KB
            reinterpret_cast<uint4*>(wlds)[u * 512 + tid] = wsw[256 + u * 512 + tid];
        if (tid < 64) { t2bs[tid] = wsf[OFF_T2B + tid]; mpb[tid] = 0.f; }
    }
    __syncthreads();

    const int wv   = tid >> 6;
    const int lane = tid & 63;
    const int c = lane & 15;
    const int g = lane >> 4;
    char* scr = scrs[wv];

    const long wave_pt0 = (long)blockIdx.x * 512 + (long)wv * 64;
    const long nrem_w = (long)N - wave_pt0;
    if (nrem_w <= 0) return;

    f32x4 t2br[4];
    #pragma unroll
    for (int mt = 0; mt < 4; ++mt)
        t2br[mt] = *reinterpret_cast<const f32x4*>(&t2bs[mt * 16 + g * 4]);

    // ---- one scatter-cursor atomic per lane, issued upfront ----
    const long ip = wave_pt0 + lane;
    const bool lane_ok = (ip < (long)N);
    int pos = 0;
    if (lane_ok) pos = atomicAdd(&cur[unq[ip]], 1);

    const f32x4 zero4 = {0.f, 0.f, 0.f, 0.f};
    float mp[16];
    #pragma unroll
    for (int j = 0; j < 16; ++j) mp[j] = 0.f;

    #pragma unroll
    for (int ti = 0; ti < 4; ++ti) {
        const bool act = (long)(ti * 16 + c) < nrem_w;

        // ---- B-frag direct from global (lanes g<2), bias slot g=2 ----
        U4 bf;
        if (g < 2) {
            const long row = act ? (wave_pt0 + ti * 16 + c) : (long)(N - 1);
            const float4* p = reinterpret_cast<const float4*>(inputs + row * 16 + g * 8);
            float4 f0 = p[0], f1 = p[1];
            asm("v_cvt_pk_bf16_f32 %0, %1, %2" : "=v"(bf.u[0]) : "v"(f0.x), "v"(f0.y));
            asm("v_cvt_pk_bf16_f32 %0, %1, %2" : "=v"(bf.u[1]) : "v"(f0.z), "v"(f0.w));
            asm("v_cvt_pk_bf16_f32 %0, %1, %2" : "=v"(bf.u[2]) : "v"(f1.x), "v"(f1.y));
            asm("v_cvt_pk_bf16_f32 %0, %1, %2" : "=v"(bf.u[3]) : "v"(f1.z), "v"(f1.w));
            if (!act) { bf.u[0] = 0u; bf.u[1] = 0u; bf.u[2] = 0u; bf.u[3] = 0u; }
        } else {
            bf.u[0] = (g == 2 && act) ? 0x00003F80u : 0u;   // k16 = 1.0 (bias)
            bf.u[1] = 0u; bf.u[2] = 0u; bf.u[3] = 0u;
        }

        // ---- scatter into segment-sorted array ----
        const int posc = __shfl(pos, ti * 16 + c, 64);
        if (g < 2 && act)
            inpS[(size_t)posc * 2 + g] = bf.u4;

        // ===== phase B: h^T = W2aF^T * in^T, relu, bf16 -> scr =====
        #pragma unroll
        for (int mt = 0; mt < 8; ++mt) {
            short8 a = *reinterpret_cast<const short8*>(&wlds[(mt * 64 + lane) * 16]);
            f32x4 hT = __builtin_amdgcn_mfma_f32_16x16x32_bf16(a, bf.s8, zero4, 0, 0, 0);
            float h0 = fmaxf(hT[0], 0.f), h1 = fmaxf(hT[1], 0.f);
            float h2 = fmaxf(hT[2], 0.f), h3 = fmaxf(hT[3], 0.f);
            unsigned lo, hi;
            asm("v_cvt_pk_bf16_f32 %0, %1, %2" : "=v"(lo) : "v"(h0), "v"(h1));
            asm("v_cvt_pk_bf16_f32 %0, %1, %2" : "=v"(hi) : "v"(h2), "v"(h3));
            *reinterpret_cast<uint2*>(
                &scr[(unsigned)(c * 256 + mt * 32 + g * 8) ^ ((unsigned)(c & 7) << 4)])
                = make_uint2(lo, hi);
        }
        __builtin_amdgcn_wave_barrier();
        __builtin_amdgcn_sched_barrier(0);

        // ===== phase C: y2^T = W2bF^T * h ; masked running max-pool =====
        f32x4 y2t[4];
        #pragma unroll
        for (int mt = 0; mt < 4; ++mt) y2t[mt] = zero4;
        #pragma unroll
        for (int ks = 0; ks < 4; ++ks) {
            short8 hb = *reinterpret_cast<const short8*>(
                &scr[(unsigned)(c * 256 + ks * 64 + g * 16) ^ ((unsigned)(c & 7) << 4)]);
            #pragma unroll
            for (int mt = 0; mt < 4; ++mt) {
                short8 a = *reinterpret_cast<const short8*>(
                    &wlds[8192 + ((mt * 4 + ks) * 64 + lane) * 16]);
                y2t[mt] = __builtin_amdgcn_mfma_f32_16x16x32_bf16(a, hb, y2t[mt], 0, 0, 0);
            }
        }
        #pragma unroll
        for (int mt = 0; mt < 4; ++mt) {
            #pragma unroll
            for (int r = 0; r < 4; ++r) {
                float v = fmaxf(y2t[mt][r] + t2br[mt][r], 0.f);
                if (act) mp[mt * 4 + r] = fmaxf(mp[mt * 4 + r], v);
            }
        }
        __builtin_amdgcn_wave_barrier();
        __builtin_amdgcn_sched_barrier(0);
    }

    // ---- block max-pool reduce: 16-lane shfl, LDS atomic, one global line ----
    #pragma unroll
    for (int j = 0; j < 16; ++j) {
        float x = mp[j];
        x = fmaxf(x, __shfl_xor(x, 1, 64));
        x = fmaxf(x, __shfl_xor(x, 2, 64));
        x = fmaxf(x, __shfl_xor(x, 4, 64));
        x = fmaxf(x, __shfl_xor(x, 8, 64));
        mp[j] = x;
    }
    if (c == 0) {
        #pragma unroll
        for (int mt = 0; mt < 4; ++mt)
            #pragma unroll
            for (int r = 0; r < 4; ++r)
                atomicMax(reinterpret_cast<int*>(&mpb[mt * 16 + g * 4 + r]),
                          __float_as_int(mp[mt * 4 + r]));
    }
    __syncthreads();
    if (tid < 64)
        atomicMax(reinterpret_cast<int*>(mpp + (blockIdx.x & 63) * 64 + tid),
                  __float_as_int(mpb[tid]));
}

// One wave per segment on SORTED bf16 inputs. w1 frags hoisted to registers:
// zero per-tile LDS. Unconditional 4 tiles/chunk for load pipelining.
__global__ __launch_bounds__(512, 4) void seg1_k(
    const uint4* __restrict__ inpS,
    const int*   __restrict__ offs,
    const uint4* __restrict__ wsw,
    const float* __restrict__ mpp,
    float* __restrict__ out,
    int S)
{
    __shared__ __align__(16) char w1lds[4096];   // w1frag [4][64][8] bf16
    __shared__ float mps[64];
    __shared__ float scr3[8][192];

    const int tid = threadIdx.x;
    if (tid < 256)
        reinterpret_cast<uint4*>(w1lds)[tid] = wsw[tid];
    if (tid < 64) {
        float m = 0.f;
        #pragma unroll
        for (int s = 0; s < 64; ++s)
            m = fmaxf(m, mpp[s * 64 + tid]);
        mps[tid] = m;
    }
    __syncthreads();

    const int wv   = tid >> 6;
    const int lane = tid & 63;
    const int seg  = blockIdx.x * 8 + wv;
    if (seg >= S) return;

    const int c = lane & 15;
    const int g = lane >> 4;

    short8 w1[4];                                 // 16 VGPRs, conflict-free reads
    #pragma unroll
    for (int mt = 0; mt < 4; ++mt)
        w1[mt] = *reinterpret_cast<const short8*>(&w1lds[(mt * 64 + lane) * 16]);

    const int start = offs[seg];
    const int end   = offs[seg + 1];

    const f32x4 zero4 = {0.f, 0.f, 0.f, 0.f};
    f32x4 as[4], am[4];
    #pragma unroll
    for (int mt = 0; mt < 4; ++mt) { as[mt] = zero4; am[mt] = zero4; }

    for (int base = start; base < end; base += 64) {
        const int nrem = end - base;
        #pragma unroll
        for (int ti = 0; ti < 4; ++ti) {
            const bool act = (ti * 16 + c) < nrem;

            U4 bf;
            if (g < 2) {
                const int row = min(base + ti * 16 + c, end - 1);
                uint4 q = inpS[(size_t)row * 2 + g];
                bf.u[0] = act ? q.x : 0u;
                bf.u[1] = act ? q.y : 0u;
                bf.u[2] = act ? q.z : 0u;
                bf.u[3] = act ? q.w : 0u;
            } else {
                bf.u[0] = (g == 2 && act) ? 0x00003F80u : 0u;
                bf.u[1] = 0u; bf.u[2] = 0u; bf.u[3] = 0u;
            }
            #pragma unroll
            for (int mt = 0; mt < 4; ++mt) {
                f32x4 y1t = __builtin_amdgcn_mfma_f32_16x16x32_bf16(w1[mt], bf.s8, zero4, 0, 0, 0);
                #pragma unroll
                for (int r = 0; r < 4; ++r) {
                    float v = fmaxf(y1t[r], 0.f);   // inactive cols contribute 0
                    as[mt][r] += v;
                    am[mt][r]  = fmaxf(am[mt][r], v);
                }
            }
        }
    }

    // ---- reduce across the 16 column-lanes ----
    #pragma unroll
    for (int mt = 0; mt < 4; ++mt) {
        #pragma unroll
        for (int r = 0; r < 4; ++r) {
            float xs = as[mt][r], xm = am[mt][r];
            xs += __shfl_xor(xs, 1, 64);  xm = fmaxf(xm, __shfl_xor(xm, 1, 64));
            xs += __shfl_xor(xs, 2, 64);  xm = fmaxf(xm, __shfl_xor(xm, 2, 64));
            xs += __shfl_xor(xs, 4, 64);  xm = fmaxf(xm, __shfl_xor(xm, 4, 64));
            xs += __shfl_xor(xs, 8, 64);  xm = fmaxf(xm, __shfl_xor(xm, 8, 64));
            as[mt][r] = xs; am[mt][r] = xm;
        }
    }

    // ---- stage channel-shuffled 192 floats, then 3 coalesced line writes ----
    float* sr = scr3[wv];
    if (c == 0) {
        #pragma unroll
        for (int mt = 0; mt < 4; ++mt)
            #pragma unroll
            for (int r = 0; r < 4; ++r) {
                const int ch = mt * 16 + g * 4 + r;
                sr[ch * 3 + 0] = as[mt][r];
                sr[ch * 3 + 1] = am[mt][r];
            }
    }
    sr[lane * 3 + 2] = mps[lane];
    __builtin_amdgcn_wave_barrier();
    asm volatile("s_waitcnt lgkmcnt(0)" ::: "memory");
    __builtin_amdgcn_sched_barrier(0);

    float* o = out + (size_t)seg * 192;
    #pragma unroll
    for (int p = 0; p < 3; ++p)
        o[p * 64 + lane] = sr[p * 64 + lane];
}

extern "C" void kernel_launch(void* const* d_in, const int* in_sizes, int n_in,
                              void* d_out, int out_size, void* d_ws, size_t ws_size,
                              hipStream_t stream)
{
    const float* inputs = (const float*)d_in[0];
    const int*   unq    = (const int*)d_in[1];
    const float* W1  = (const float*)d_in[3];
    const float* g1  = (const float*)d_in[4];
    const float* b1  = (const float*)d_in[5];
    const float* m1  = (const float*)d_in[6];
    const float* v1  = (const float*)d_in[7];
    const float* W2a = (const float*)d_in[8];
    const float* g2a = (const float*)d_in[9];
    const float* b2a = (const float*)d_in[10];
    const float* m2a = (const float*)d_in[11];
    const float* v2a = (const float*)d_in[12];
    const float* W2b = (const float*)d_in[13];
    const float* g2b = (const float*)d_in[14];
    const float* b2b = (const float*)d_in[15];
    const float* m2b = (const float*)d_in[16];
    const float* v2b = (const float*)d_in[17];

    float* wsf = (float*)d_ws;
    float* out = (float*)d_out;
    const int N = in_sizes[0] / 16;
    const int S = out_size / 192;

    float* mpp  = wsf + OFF_MPP;
    int*   cnt  = (int*)(wsf + OFF_CNT);
    int*   offs = (int*)(wsf + OFF_OFFS);
    int*   cur  = (int*)(wsf + OFF_CUR);
    uint4* inpS = (uint4*)(wsf + OFF_INPS);

    // zero mpp + cnt (contiguous region)
    hipMemsetAsync(mpp, 0, (size_t)(OFF_CNT + 20016 - OFF_MPP) * sizeof(float), stream);

    init_k<<<1 + (N + 255) / 256, 256, 0, stream>>>(
        W1, g1, b1, m1, v1, W2a, g2a, b2a, m2a, v2a, W2b, g2b, b2b, m2b, v2b,
        (unsigned short*)d_ws, wsf, unq, cnt, N);

    scan_k<<<1, 1024, 0, stream>>>(cnt, offs, cur, S);

    scatbr2_k<<<(N + 511) / 512, 512, 0, stream>>>(inputs, unq, cur, inpS,
                                                   (const uint4*)d_ws, wsf, mpp, N);

    seg1_k<<<(S + 7) / 8, 512, 0, stream>>>(inpS, offs, (const uint4*)d_ws,
                                            mpp, out, S);
}

// Round 8
// 218.724 us; speedup vs baseline: 1.1864x; 1.1864x over previous
//
#include <hip/hip_runtime.h>

#define EPS 1e-3f

// ---------------- workspace layout (float slots) ----------------
// bytes 0..28671 : bf16 fused weights in FRAG-MAJOR layout (init_k block 0)
//   w1frag  u16[4 frag][64 lane][8]   @ u16 0     (4KB)
//   w2afrag u16[8 frag][64 lane][8]   @ u16 2048  (8KB)
//   w2bfrag u16[16 frag][64 lane][8]  @ u16 6144  (16KB)
// element j of frag f, lane(c,g): weight[row = mt*16+c][k = ks*32 + g*8 + j]
#define OFF_T2B    7168              // f32[64]
#define OFF_MPP    7232              // f32[64][64] max-pool partials (memset)
#define OFF_MPF    11328             // f32[64]     final max-pool (fin_k)
#define OFF_CNT    11392             // i32[20016]  histogram (memset w/ mpp)
#define OFF_OFFS   31408             // i32[S+1] CSR offsets
#define OFF_CUR    51424             // i32[S]   scatter cursors
#define OFF_INPS   71424             // bf16[N][16] sorted inputs (32B/pt)

typedef short short8 __attribute__((ext_vector_type(8)));
typedef float f32x4 __attribute__((ext_vector_type(4)));

union U4 { unsigned u[4]; short8 s8; uint4 u4; };

__device__ inline unsigned short f2bf(float f) {           // RNE f32->bf16
    unsigned u = __float_as_uint(f);
    return (unsigned short)((u + 0x7FFFu + ((u >> 16) & 1u)) >> 16);
}

// block 0: fuse BN into bf16 weights (frag-major); blocks 1..: histogram
__global__ __launch_bounds__(256) void init_k(
    const float* __restrict__ W1,
    const float* __restrict__ g1, const float* __restrict__ b1,
    const float* __restrict__ m1, const float* __restrict__ v1,
    const float* __restrict__ W2a,
    const float* __restrict__ g2a, const float* __restrict__ b2a,
    const float* __restrict__ m2a, const float* __restrict__ v2a,
    const float* __restrict__ W2b,
    const float* __restrict__ g2b, const float* __restrict__ b2b,
    const float* __restrict__ m2b, const float* __restrict__ v2b,
    unsigned short* __restrict__ wsu, float* __restrict__ wsf,
    const int* __restrict__ unq, int* __restrict__ cnt, int N)
{
    const int t = threadIdx.x;
    if (blockIdx.x == 0) {
        for (int i = t; i < 2048; i += 256) {           // w1frag
            int mt = i >> 9, lane = (i >> 3) & 63, j = i & 7;
            int c = lane & 15, g = lane >> 4;
            int k = g * 8 + j, ch = mt * 16 + c;
            float s = g1[ch] * rsqrtf(v1[ch] + EPS);
            float val = (k < 16) ? W1[k * 64 + ch] * s
                      : (k == 16 ? b1[ch] - m1[ch] * s : 0.f);
            wsu[i] = f2bf(val);
        }
        for (int i = t; i < 4096; i += 256) {           // w2afrag
            int mt = i >> 9, lane = (i >> 3) & 63, j = i & 7;
            int c = lane & 15, g = lane >> 4;
            int k = g * 8 + j, ch = mt * 16 + c;
            float s = g2a[ch] * rsqrtf(v2a[ch] + EPS);
            float val = (k < 16) ? W2a[k * 128 + ch] * s
                      : (k == 16 ? b2a[ch] - m2a[ch] * s : 0.f);
            wsu[2048 + i] = f2bf(val);
        }
        for (int i = t; i < 8192; i += 256) {           // w2bfrag
            int f = i >> 9, lane = (i >> 3) & 63, j = i & 7;
            int mt = f >> 2, ks = f & 3;
            int c = lane & 15, g = lane >> 4;
            int k = ks * 32 + g * 8 + j, ch = mt * 16 + c;
            float s = g2b[ch] * rsqrtf(v2b[ch] + EPS);
            wsu[6144 + i] = f2bf(W2b[k * 64 + ch] * s);
        }
        if (t < 64) {
            float s = g2b[t] * rsqrtf(v2b[t] + EPS);
            wsf[OFF_T2B + t] = b2b[t] - m2b[t] * s;
        }
    } else {
        const int i = (blockIdx.x - 1) * 256 + t;
        if (i < N) atomicAdd(&cnt[unq[i]], 1);
    }
}

// serial-per-thread two-pass scan
__global__ __launch_bounds__(1024) void scan_k(
    const int* __restrict__ cnt, int* __restrict__ offs,
    int* __restrict__ cur, int S)
{
    __shared__ int tot[1024];
    const int t = threadIdx.x;
    const int E = (S + 1023) >> 10;
    const int i0 = t * E;
    int run = 0;
    for (int j = 0; j < E; ++j) {
        const int i = i0 + j;
        run += (i < S) ? cnt[i] : 0;
    }
    tot[t] = run;
    __syncthreads();
    for (int d = 1; d < 1024; d <<= 1) {
        int x = (t >= d) ? tot[t - d] : 0;
        __syncthreads();
        tot[t] += x;
        __syncthreads();
    }
    int base = (t == 0) ? 0 : tot[t - 1];
    for (int j = 0; j < E; ++j) {
        const int i = i0 + j;
        if (i < S) {
            offs[i] = base;
            cur[i]  = base;
            base += cnt[i];
        }
    }
    if (t == 1023) offs[S] = tot[1023];
}

// Fused scatter + branch2 + global max-pool. All weight reads are
// conflict-free frag-major ds_read_b128 ((f*64+lane)*16). Scatter atomics
// batched once per wave (1/lane) so latency hides under the tile loop.
__global__ __launch_bounds__(512, 2) void scatbr2_k(
    const float* __restrict__ inputs,
    const int*   __restrict__ unq,
    int*         __restrict__ cur,
    uint4*       __restrict__ inpS,
    const uint4* __restrict__ wsw,
    const float* __restrict__ wsf,
    float* __restrict__ mpp,
    int N)
{
    __shared__ __align__(16) char wlds[24576];   // w2afrag 8KB @0, w2bfrag 16KB @8192
    __shared__ float t2bs[64];
    __shared__ float mpb[64];
    __shared__ __align__(16) char scrs[8][4096]; // per-wave h staging (bf16)

    const int tid = threadIdx.x;
    {
        #pragma unroll
        for (int u = 0; u < 3; ++u)              // 1536 uint4 = 24KB
            reinterpret_cast<uint4*>(wlds)[u * 512 + tid] = wsw[256 + u * 512 + tid];
        if (tid < 64) { t2bs[tid] = wsf[OFF_T2B + tid]; mpb[tid] = 0.f; }
    }
    __syncthreads();

    const int wv   = tid >> 6;
    const int lane = tid & 63;
    const int c = lane & 15;
    const int g = lane >> 4;
    char* scr = scrs[wv];

    const long wave_pt0 = (long)blockIdx.x * 512 + (long)wv * 64;
    const long nrem_w = (long)N - wave_pt0;
    if (nrem_w <= 0) return;

    f32x4 t2br[4];
    #pragma unroll
    for (int mt = 0; mt < 4; ++mt)
        t2br[mt] = *reinterpret_cast<const f32x4*>(&t2bs[mt * 16 + g * 4]);

    // ---- one scatter-cursor atomic per lane, issued upfront ----
    const long ip = wave_pt0 + lane;
    const bool lane_ok = (ip < (long)N);
    int pos = 0;
    if (lane_ok) pos = atomicAdd(&cur[unq[ip]], 1);

    const f32x4 zero4 = {0.f, 0.f, 0.f, 0.f};
    float mp[16];
    #pragma unroll
    for (int j = 0; j < 16; ++j) mp[j] = 0.f;

    #pragma unroll
    for (int ti = 0; ti < 4; ++ti) {
        if ((long)ti * 16 >= nrem_w) break;              // wave-uniform
        const bool act = (long)(ti * 16 + c) < nrem_w;

        // ---- B-frag direct from global (lanes g<2), bias slot g=2 ----
        U4 bf;
        if (g < 2) {
            const long row = act ? (wave_pt0 + ti * 16 + c) : (long)(N - 1);
            const float4* p = reinterpret_cast<const float4*>(inputs + row * 16 + g * 8);
            float4 f0 = p[0], f1 = p[1];
            asm("v_cvt_pk_bf16_f32 %0, %1, %2" : "=v"(bf.u[0]) : "v"(f0.x), "v"(f0.y));
            asm("v_cvt_pk_bf16_f32 %0, %1, %2" : "=v"(bf.u[1]) : "v"(f0.z), "v"(f0.w));
            asm("v_cvt_pk_bf16_f32 %0, %1, %2" : "=v"(bf.u[2]) : "v"(f1.x), "v"(f1.y));
            asm("v_cvt_pk_bf16_f32 %0, %1, %2" : "=v"(bf.u[3]) : "v"(f1.z), "v"(f1.w));
            if (!act) { bf.u[0] = 0u; bf.u[1] = 0u; bf.u[2] = 0u; bf.u[3] = 0u; }
        } else {
            bf.u[0] = (g == 2 && act) ? 0x00003F80u : 0u;   // k16 = 1.0 (bias)
            bf.u[1] = 0u; bf.u[2] = 0u; bf.u[3] = 0u;
        }

        // ---- scatter into segment-sorted array ----
        const int posc = __shfl(pos, ti * 16 + c, 64);
        if (g < 2 && act)
            inpS[(size_t)posc * 2 + g] = bf.u4;

        // ===== phase B: h^T = W2aF^T * in^T, relu, bf16 -> scr =====
        #pragma unroll
        for (int mt = 0; mt < 8; ++mt) {
            short8 a = *reinterpret_cast<const short8*>(&wlds[(mt * 64 + lane) * 16]);
            f32x4 hT = __builtin_amdgcn_mfma_f32_16x16x32_bf16(a, bf.s8, zero4, 0, 0, 0);
            float h0 = fmaxf(hT[0], 0.f), h1 = fmaxf(hT[1], 0.f);
            float h2 = fmaxf(hT[2], 0.f), h3 = fmaxf(hT[3], 0.f);
            unsigned lo, hi;
            asm("v_cvt_pk_bf16_f32 %0, %1, %2" : "=v"(lo) : "v"(h0), "v"(h1));
            asm("v_cvt_pk_bf16_f32 %0, %1, %2" : "=v"(hi) : "v"(h2), "v"(h3));
            *reinterpret_cast<uint2*>(
                &scr[(unsigned)(c * 256 + mt * 32 + g * 8) ^ ((unsigned)(c & 7) << 4)])
                = make_uint2(lo, hi);
        }
        __builtin_amdgcn_wave_barrier();
        __builtin_amdgcn_sched_barrier(0);

        // ===== phase C: y2^T = W2bF^T * h ; masked running max-pool =====
        f32x4 y2t[4];
        #pragma unroll
        for (int mt = 0; mt < 4; ++mt) y2t[mt] = zero4;
        #pragma unroll
        for (int ks = 0; ks < 4; ++ks) {
            short8 hb = *reinterpret_cast<const short8*>(
                &scr[(unsigned)(c * 256 + ks * 64 + g * 16) ^ ((unsigned)(c & 7) << 4)]);
            #pragma unroll
            for (int mt = 0; mt < 4; ++mt) {
                short8 a = *reinterpret_cast<const short8*>(
                    &wlds[8192 + ((mt * 4 + ks) * 64 + lane) * 16]);
                y2t[mt] = __builtin_amdgcn_mfma_f32_16x16x32_bf16(a, hb, y2t[mt], 0, 0, 0);
            }
        }
        #pragma unroll
        for (int mt = 0; mt < 4; ++mt) {
            #pragma unroll
            for (int r = 0; r < 4; ++r) {
                float v = fmaxf(y2t[mt][r] + t2br[mt][r], 0.f);
                if (act) mp[mt * 4 + r] = fmaxf(mp[mt * 4 + r], v);
            }
        }
        __builtin_amdgcn_wave_barrier();
        __builtin_amdgcn_sched_barrier(0);
    }

    // ---- block max-pool reduce: 16-lane shfl, LDS atomic, one global line ----
    #pragma unroll
    for (int j = 0; j < 16; ++j) {
        float x = mp[j];
        x = fmaxf(x, __shfl_xor(x, 1, 64));
        x = fmaxf(x, __shfl_xor(x, 2, 64));
        x = fmaxf(x, __shfl_xor(x, 4, 64));
        x = fmaxf(x, __shfl_xor(x, 8, 64));
        mp[j] = x;
    }
    if (c == 0) {
        #pragma unroll
        for (int mt = 0; mt < 4; ++mt)
            #pragma unroll
            for (int r = 0; r < 4; ++r)
                atomicMax(reinterpret_cast<int*>(&mpb[mt * 16 + g * 4 + r]),
                          __float_as_int(mp[mt * 4 + r]));
    }
    __syncthreads();
    if (tid < 64)
        atomicMax(reinterpret_cast<int*>(mpp + (blockIdx.x & 63) * 64 + tid),
                  __float_as_int(mpb[tid]));
}

// finalize global max-pool: 64 slots -> 64 channels
__global__ __launch_bounds__(64) void fin_k(
    const float* __restrict__ mpp, float* __restrict__ mpf)
{
    const int t = threadIdx.x;
    float m = 0.f;
    #pragma unroll
    for (int s = 0; s < 64; ++s)
        m = fmaxf(m, mpp[s * 64 + t]);
    mpf[t] = m;
}

// One wave per segment on SORTED bf16 inputs. No block-shared state, no
// __syncthreads: w1 frags per-lane from global (L2-hot 4KB), mp from mpf.
// 4 waves/block, minimal LDS -> high occupancy for latency hiding.
__global__ __launch_bounds__(256, 6) void seg1_k(
    const uint4* __restrict__ inpS,
    const int*   __restrict__ offs,
    const uint4* __restrict__ wsw,
    const float* __restrict__ mpf,
    float* __restrict__ out,
    int S)
{
    __shared__ float scr3[4][192];

    const int tid  = threadIdx.x;
    const int wv   = tid >> 6;
    const int lane = tid & 63;
    const int seg  = blockIdx.x * 4 + wv;
    if (seg >= S) return;

    const int c = lane & 15;
    const int g = lane >> 4;

    short8 w1[4];                                 // 16 VGPRs, from global (L2-hot)
    #pragma unroll
    for (int mt = 0; mt < 4; ++mt) {
        U4 t; t.u4 = wsw[mt * 64 + lane]; w1[mt] = t.s8;
    }
    const float mpl = mpf[lane];

    const int su    = __builtin_amdgcn_readfirstlane(seg);
    const int start = offs[su];
    const int end   = offs[su + 1];

    const f32x4 zero4 = {0.f, 0.f, 0.f, 0.f};
    f32x4 as[4], am[4];
    #pragma unroll
    for (int mt = 0; mt < 4; ++mt) { as[mt] = zero4; am[mt] = zero4; }

    for (int base = start; base < end; base += 64) {
        const int nrem = end - base;
        #pragma unroll
        for (int ti = 0; ti < 4; ++ti) {
            if (ti * 16 >= nrem) break;                 // wave-uniform
            const bool act = (ti * 16 + c) < nrem;

            U4 bf;
            if (g < 2) {
                const int row = min(base + ti * 16 + c, end - 1);
                uint4 q = inpS[(size_t)row * 2 + g];
                bf.u[0] = act ? q.x : 0u;
                bf.u[1] = act ? q.y : 0u;
                bf.u[2] = act ? q.z : 0u;
                bf.u[3] = act ? q.w : 0u;
            } else {
                bf.u[0] = (g == 2 && act) ? 0x00003F80u : 0u;
                bf.u[1] = 0u; bf.u[2] = 0u; bf.u[3] = 0u;
            }
            #pragma unroll
            for (int mt = 0; mt < 4; ++mt) {
                f32x4 y1t = __builtin_amdgcn_mfma_f32_16x16x32_bf16(w1[mt], bf.s8, zero4, 0, 0, 0);
                #pragma unroll
                for (int r = 0; r < 4; ++r) {
                    float v = fmaxf(y1t[r], 0.f);   // inactive cols contribute 0
                    as[mt][r] += v;
                    am[mt][r]  = fmaxf(am[mt][r], v);
                }
            }
        }
    }

    // ---- reduce across the 16 column-lanes ----
    #pragma unroll
    for (int mt = 0; mt < 4; ++mt) {
        #pragma unroll
        for (int r = 0; r < 4; ++r) {
            float xs = as[mt][r], xm = am[mt][r];
            xs += __shfl_xor(xs, 1, 64);  xm = fmaxf(xm, __shfl_xor(xm, 1, 64));
            xs += __shfl_xor(xs, 2, 64);  xm = fmaxf(xm, __shfl_xor(xm, 2, 64));
            xs += __shfl_xor(xs, 4, 64);  xm = fmaxf(xm, __shfl_xor(xm, 4, 64));
            xs += __shfl_xor(xs, 8, 64);  xm = fmaxf(xm, __shfl_xor(xm, 8, 64));
            as[mt][r] = xs; am[mt][r] = xm;
        }
    }

    // ---- stage channel-shuffled 192 floats, then 3 coalesced line writes ----
    float* sr = scr3[wv];
    if (c == 0) {
        #pragma unroll
        for (int mt = 0; mt < 4; ++mt)
            #pragma unroll
            for (int r = 0; r < 4; ++r) {
                const int ch = mt * 16 + g * 4 + r;
                sr[ch * 3 + 0] = as[mt][r];
                sr[ch * 3 + 1] = am[mt][r];
            }
    }
    sr[lane * 3 + 2] = mpl;
    __builtin_amdgcn_wave_barrier();
    asm volatile("s_waitcnt lgkmcnt(0)" ::: "memory");
    __builtin_amdgcn_sched_barrier(0);

    float* o = out + (size_t)seg * 192;
    #pragma unroll
    for (int p = 0; p < 3; ++p)
        o[p * 64 + lane] = sr[p * 64 + lane];
}

extern "C" void kernel_launch(void* const* d_in, const int* in_sizes, int n_in,
                              void* d_out, int out_size, void* d_ws, size_t ws_size,
                              hipStream_t stream)
{
    const float* inputs = (const float*)d_in[0];
    const int*   unq    = (const int*)d_in[1];
    const float* W1  = (const float*)d_in[3];
    const float* g1  = (const float*)d_in[4];
    const float* b1  = (const float*)d_in[5];
    const float* m1  = (const float*)d_in[6];
    const float* v1  = (const float*)d_in[7];
    const float* W2a = (const float*)d_in[8];
    const float* g2a = (const float*)d_in[9];
    const float* b2a = (const float*)d_in[10];
    const float* m2a = (const float*)d_in[11];
    const float* v2a = (const float*)d_in[12];
    const float* W2b = (const float*)d_in[13];
    const float* g2b = (const float*)d_in[14];
    const float* b2b = (const float*)d_in[15];
    const float* m2b = (const float*)d_in[16];
    const float* v2b = (const float*)d_in[17];

    float* wsf = (float*)d_ws;
    float* out = (float*)d_out;
    const int N = in_sizes[0] / 16;
    const int S = out_size / 192;

    float* mpp  = wsf + OFF_MPP;
    float* mpf  = wsf + OFF_MPF;
    int*   cnt  = (int*)(wsf + OFF_CNT);
    int*   offs = (int*)(wsf + OFF_OFFS);
    int*   cur  = (int*)(wsf + OFF_CUR);
    uint4* inpS = (uint4*)(wsf + OFF_INPS);

    // zero mpp + mpf + cnt (contiguous region)
    hipMemsetAsync(mpp, 0, (size_t)(OFF_CNT + 20016 - OFF_MPP) * sizeof(float), stream);

    init_k<<<1 + (N + 255) / 256, 256, 0, stream>>>(
        W1, g1, b1, m1, v1, W2a, g2a, b2a, m2a, v2a, W2b, g2b, b2b, m2b, v2b,
        (unsigned short*)d_ws, wsf, unq, cnt, N);

    scan_k<<<1, 1024, 0, stream>>>(cnt, offs, cur, S);

    scatbr2_k<<<(N + 511) / 512, 512, 0, stream>>>(inputs, unq, cur, inpS,
                                                   (const uint4*)d_ws, wsf, mpp, N);

    fin_k<<<1, 64, 0, stream>>>(mpp, mpf);

    seg1_k<<<(S + 3) / 4, 256, 0, stream>>>(inpS, offs, (const uint4*)d_ws,
                                            mpf, out, S);
}

// Round 9
// 208.936 us; speedup vs baseline: 1.2420x; 1.0468x over previous
//
#include <hip/hip_runtime.h>

#define EPS 1e-3f

// ---------------- workspace layout (float slots) ----------------
// bytes 0..28671 : bf16 fused weights in FRAG-MAJOR layout (init_k block 0)
//   w1frag  u16[4 frag][64 lane][8]   @ u16 0     (4KB)
//   w2afrag u16[8 frag][64 lane][8]   @ u16 2048  (8KB)
//   w2bfrag u16[16 frag][64 lane][8]  @ u16 6144  (16KB)
// element j of frag f, lane(c,g): weight[row = mt*16+c][k = ks*32 + g*8 + j]
#define OFF_T2B    7168              // f32[64]
#define OFF_MPP    7232              // f32[64][64] max-pool partials (memset)
#define OFF_MPF    11328             // f32[64]     final max-pool (fin_k)
#define OFF_CNT    11392             // i32[20016]  histogram (memset w/ mpp)
#define OFF_OFFS   31408             // i32[S+1] CSR offsets
#define OFF_CUR    51424             // i32[S]   scatter cursors
#define OFF_INPS   71424             // bf16[N][16] sorted inputs (32B/pt)

typedef short short8 __attribute__((ext_vector_type(8)));
typedef float f32x4 __attribute__((ext_vector_type(4)));

union U4 { unsigned u[4]; short8 s8; uint4 u4; };

__device__ inline unsigned short f2bf(float f) {           // RNE f32->bf16
    unsigned u = __float_as_uint(f);
    return (unsigned short)((u + 0x7FFFu + ((u >> 16) & 1u)) >> 16);
}

// block 0: fuse BN into bf16 weights (frag-major); blocks 1..: histogram
__global__ __launch_bounds__(256) void init_k(
    const float* __restrict__ W1,
    const float* __restrict__ g1, const float* __restrict__ b1,
    const float* __restrict__ m1, const float* __restrict__ v1,
    const float* __restrict__ W2a,
    const float* __restrict__ g2a, const float* __restrict__ b2a,
    const float* __restrict__ m2a, const float* __restrict__ v2a,
    const float* __restrict__ W2b,
    const float* __restrict__ g2b, const float* __restrict__ b2b,
    const float* __restrict__ m2b, const float* __restrict__ v2b,
    unsigned short* __restrict__ wsu, float* __restrict__ wsf,
    const int* __restrict__ unq, int* __restrict__ cnt, int N)
{
    const int t = threadIdx.x;
    if (blockIdx.x == 0) {
        for (int i = t; i < 2048; i += 256) {           // w1frag
            int mt = i >> 9, lane = (i >> 3) & 63, j = i & 7;
            int c = lane & 15, g = lane >> 4;
            int k = g * 8 + j, ch = mt * 16 + c;
            float s = g1[ch] * rsqrtf(v1[ch] + EPS);
            float val = (k < 16) ? W1[k * 64 + ch] * s
                      : (k == 16 ? b1[ch] - m1[ch] * s : 0.f);
            wsu[i] = f2bf(val);
        }
        for (int i = t; i < 4096; i += 256) {           // w2afrag
            int mt = i >> 9, lane = (i >> 3) & 63, j = i & 7;
            int c = lane & 15, g = lane >> 4;
            int k = g * 8 + j, ch = mt * 16 + c;
            float s = g2a[ch] * rsqrtf(v2a[ch] + EPS);
            float val = (k < 16) ? W2a[k * 128 + ch] * s
                      : (k == 16 ? b2a[ch] - m2a[ch] * s : 0.f);
            wsu[2048 + i] = f2bf(val);
        }
        for (int i = t; i < 8192; i += 256) {           // w2bfrag
            int f = i >> 9, lane = (i >> 3) & 63, j = i & 7;
            int mt = f >> 2, ks = f & 3;
            int c = lane & 15, g = lane >> 4;
            int k = ks * 32 + g * 8 + j, ch = mt * 16 + c;
            float s = g2b[ch] * rsqrtf(v2b[ch] + EPS);
            wsu[6144 + i] = f2bf(W2b[k * 64 + ch] * s);
        }
        if (t < 64) {
            float s = g2b[t] * rsqrtf(v2b[t] + EPS);
            wsf[OFF_T2B + t] = b2b[t] - m2b[t] * s;
        }
    } else {
        const int i = (blockIdx.x - 1) * 256 + t;
        if (i < N) atomicAdd(&cnt[unq[i]], 1);
    }
}

// serial-per-thread two-pass scan
__global__ __launch_bounds__(1024) void scan_k(
    const int* __restrict__ cnt, int* __restrict__ offs,
    int* __restrict__ cur, int S)
{
    __shared__ int tot[1024];
    const int t = threadIdx.x;
    const int E = (S + 1023) >> 10;
    const int i0 = t * E;
    int run = 0;
    for (int j = 0; j < E; ++j) {
        const int i = i0 + j;
        run += (i < S) ? cnt[i] : 0;
    }
    tot[t] = run;
    __syncthreads();
    for (int d = 1; d < 1024; d <<= 1) {
        int x = (t >= d) ? tot[t - d] : 0;
        __syncthreads();
        tot[t] += x;
        __syncthreads();
    }
    int base = (t == 0) ? 0 : tot[t - 1];
    for (int j = 0; j < E; ++j) {
        const int i = i0 + j;
        if (i < S) {
            offs[i] = base;
            cur[i]  = base;
            base += cnt[i];
        }
    }
    if (t == 1023) offs[S] = tot[1023];
}

// Fused scatter + branch2 + global max-pool.
// Weights fully register-resident (96 VGPR, loaded once from L2-hot global).
// Only LDS use: 2x4KB/wave double-buffered h-transpose scratch, laid out so
// reads are canonical lane*16 (conflict-free b128) and writes are <=2-way.
__global__ __launch_bounds__(256, 3) void scatbr2_k(
    const float* __restrict__ inputs,
    const int*   __restrict__ unq,
    int*         __restrict__ cur,
    uint4*       __restrict__ inpS,
    const uint4* __restrict__ wsw,
    const float* __restrict__ wsf,
    float* __restrict__ mpp,
    int N)
{
    __shared__ __align__(16) char scrs[4][2][4096]; // [wave][buf]: [ks][slot=g*16+c][16B]
    __shared__ float mpb[64];

    const int tid  = threadIdx.x;
    const int wv   = tid >> 6;
    const int lane = tid & 63;
    const int c = lane & 15;
    const int g = lane >> 4;

    if (tid < 64) mpb[tid] = 0.f;
    __syncthreads();

    // ---- all weights into VGPRs (frag-major, per-lane 16B slices) ----
    short8 w2a[8], w2b[16];
    #pragma unroll
    for (int mt = 0; mt < 8; ++mt) {
        U4 t; t.u4 = wsw[256 + mt * 64 + lane]; w2a[mt] = t.s8;
    }
    #pragma unroll
    for (int f = 0; f < 16; ++f) {
        U4 t; t.u4 = wsw[768 + f * 64 + lane]; w2b[f] = t.s8;
    }

    const long wave_pt0 = (long)blockIdx.x * 256 + (long)wv * 64;
    const long nrem_w = (long)N - wave_pt0;

    // ---- one scatter-cursor atomic per lane, issued upfront ----
    const long ip = wave_pt0 + lane;
    const bool lane_ok = (ip < (long)N) && (nrem_w > 0);
    int pos = 0;
    if (lane_ok) pos = atomicAdd(&cur[unq[ip]], 1);

    const f32x4 zero4 = {0.f, 0.f, 0.f, 0.f};
    float mp[16];
    #pragma unroll
    for (int j = 0; j < 16; ++j) mp[j] = -3.0e38f;   // bias deferred -> raw max

    #pragma unroll
    for (int ti = 0; ti < 4; ++ti) {
        if ((long)ti * 16 >= nrem_w) break;              // wave-uniform
        const bool act = (long)(ti * 16 + c) < nrem_w;
        char* scr = scrs[wv][ti & 1];

        // ---- B-frag direct from global (lanes g<2), bias slot g=2 ----
        U4 bf;
        if (g < 2) {
            const long row = act ? (wave_pt0 + ti * 16 + c) : (long)(N - 1);
            const float4* p = reinterpret_cast<const float4*>(inputs + row * 16 + g * 8);
            float4 f0 = p[0], f1 = p[1];
            asm("v_cvt_pk_bf16_f32 %0, %1, %2" : "=v"(bf.u[0]) : "v"(f0.x), "v"(f0.y));
            asm("v_cvt_pk_bf16_f32 %0, %1, %2" : "=v"(bf.u[1]) : "v"(f0.z), "v"(f0.w));
            asm("v_cvt_pk_bf16_f32 %0, %1, %2" : "=v"(bf.u[2]) : "v"(f1.x), "v"(f1.y));
            asm("v_cvt_pk_bf16_f32 %0, %1, %2" : "=v"(bf.u[3]) : "v"(f1.z), "v"(f1.w));
            if (!act) { bf.u[0] = 0u; bf.u[1] = 0u; bf.u[2] = 0u; bf.u[3] = 0u; }
        } else {
            bf.u[0] = (g == 2 && act) ? 0x00003F80u : 0u;   // k16 = 1.0 (bias)
            bf.u[1] = 0u; bf.u[2] = 0u; bf.u[3] = 0u;
        }

        // ---- scatter into segment-sorted array ----
        const int posc = __shfl(pos, ti * 16 + c, 64);
        if (g < 2 && act)
            inpS[(size_t)posc * 2 + g] = bf.u4;

        // ===== phase B: h^T = W2aF^T * in^T, relu, bf16 -> scr =====
        // store ch = mt*16 + g*4 + r at scr[ks=mt>>1][slot = gw*16+c][(g&1)*8 + 2r]
        // with gw = 2*(mt&1) + (g>>1): read side is then exactly lane*16.
        __builtin_amdgcn_wave_barrier();
        #pragma unroll
        for (int mt = 0; mt < 8; ++mt) {
            f32x4 hT = __builtin_amdgcn_mfma_f32_16x16x32_bf16(w2a[mt], bf.s8, zero4, 0, 0, 0);
            float h0 = fmaxf(hT[0], 0.f), h1 = fmaxf(hT[1], 0.f);
            float h2 = fmaxf(hT[2], 0.f), h3 = fmaxf(hT[3], 0.f);
            unsigned lo, hi;
            asm("v_cvt_pk_bf16_f32 %0, %1, %2" : "=v"(lo) : "v"(h0), "v"(h1));
            asm("v_cvt_pk_bf16_f32 %0, %1, %2" : "=v"(hi) : "v"(h2), "v"(h3));
            const int gw = 2 * (mt & 1) + (g >> 1);
            *reinterpret_cast<uint2*>(
                &scr[(mt >> 1) * 1024 + (gw * 16 + c) * 16 + (g & 1) * 8])
                = make_uint2(lo, hi);
        }
        __builtin_amdgcn_wave_barrier();

        // ===== phase C: y2raw^T = W2bF^T * h ; raw running max (bias deferred) =====
        f32x4 y2t[4];
        #pragma unroll
        for (int mt = 0; mt < 4; ++mt) y2t[mt] = zero4;
        #pragma unroll
        for (int ks = 0; ks < 4; ++ks) {
            short8 hb = *reinterpret_cast<const short8*>(&scr[ks * 1024 + lane * 16]);
            #pragma unroll
            for (int mt = 0; mt < 4; ++mt)
                y2t[mt] = __builtin_amdgcn_mfma_f32_16x16x32_bf16(w2b[mt * 4 + ks], hb, y2t[mt], 0, 0, 0);
        }
        #pragma unroll
        for (int mt = 0; mt < 4; ++mt) {
            #pragma unroll
            for (int r = 0; r < 4; ++r)
                mp[mt * 4 + r] = act ? fmaxf(mp[mt * 4 + r], y2t[mt][r]) : mp[mt * 4 + r];
        }
        __builtin_amdgcn_wave_barrier();
    }

    // ---- reduce raw max over the 16 column-lanes ----
    #pragma unroll
    for (int j = 0; j < 16; ++j) {
        float x = mp[j];
        x = fmaxf(x, __shfl_xor(x, 1, 64));
        x = fmaxf(x, __shfl_xor(x, 2, 64));
        x = fmaxf(x, __shfl_xor(x, 4, 64));
        x = fmaxf(x, __shfl_xor(x, 8, 64));
        mp[j] = x;
    }
    if (c == 0) {   // apply deferred bias + relu, then block-level LDS max
        #pragma unroll
        for (int mt = 0; mt < 4; ++mt)
            #pragma unroll
            for (int r = 0; r < 4; ++r) {
                const int ch = mt * 16 + g * 4 + r;
                const float v = fmaxf(mp[mt * 4 + r] + wsf[OFF_T2B + ch], 0.f);
                atomicMax(reinterpret_cast<int*>(&mpb[ch]), __float_as_int(v));
            }
    }
    __syncthreads();
    if (tid < 64)
        atomicMax(reinterpret_cast<int*>(mpp + (blockIdx.x & 63) * 64 + tid),
                  __float_as_int(mpb[tid]));
}

// finalize global max-pool: 64 slots -> 64 channels
__global__ __launch_bounds__(64) void fin_k(
    const float* __restrict__ mpp, float* __restrict__ mpf)
{
    const int t = threadIdx.x;
    float m = 0.f;
    #pragma unroll
    for (int s = 0; s < 64; ++s)
        m = fmaxf(m, mpp[s * 64 + t]);
    mpf[t] = m;
}

// One wave per segment on SORTED bf16 inputs. No block-shared state, no
// __syncthreads: w1 frags per-lane from global (L2-hot 4KB), mp from mpf.
__global__ __launch_bounds__(256, 6) void seg1_k(
    const uint4* __restrict__ inpS,
    const int*   __restrict__ offs,
    const uint4* __restrict__ wsw,
    const float* __restrict__ mpf,
    float* __restrict__ out,
    int S)
{
    __shared__ float scr3[4][192];

    const int tid  = threadIdx.x;
    const int wv   = tid >> 6;
    const int lane = tid & 63;
    const int seg  = blockIdx.x * 4 + wv;
    if (seg >= S) return;

    const int c = lane & 15;
    const int g = lane >> 4;

    short8 w1[4];                                 // 16 VGPRs, from global (L2-hot)
    #pragma unroll
    for (int mt = 0; mt < 4; ++mt) {
        U4 t; t.u4 = wsw[mt * 64 + lane]; w1[mt] = t.s8;
    }
    const float mpl = mpf[lane];

    const int su    = __builtin_amdgcn_readfirstlane(seg);
    const int start = offs[su];
    const int end   = offs[su + 1];

    const f32x4 zero4 = {0.f, 0.f, 0.f, 0.f};
    f32x4 as[4], am[4];
    #pragma unroll
    for (int mt = 0; mt < 4; ++mt) { as[mt] = zero4; am[mt] = zero4; }

    for (int base = start; base < end; base += 64) {
        const int nrem = end - base;
        #pragma unroll
        for (int ti = 0; ti < 4; ++ti) {
            if (ti * 16 >= nrem) break;                 // wave-uniform
            const bool act = (ti * 16 + c) < nrem;

            U4 bf;
            if (g < 2) {
                const int row = min(base + ti * 16 + c, end - 1);
                uint4 q = inpS[(size_t)row * 2 + g];
                bf.u[0] = act ? q.x : 0u;
                bf.u[1] = act ? q.y : 0u;
                bf.u[2] = act ? q.z : 0u;
                bf.u[3] = act ? q.w : 0u;
            } else {
                bf.u[0] = (g == 2 && act) ? 0x00003F80u : 0u;
                bf.u[1] = 0u; bf.u[2] = 0u; bf.u[3] = 0u;
            }
            #pragma unroll
            for (int mt = 0; mt < 4; ++mt) {
                f32x4 y1t = __builtin_amdgcn_mfma_f32_16x16x32_bf16(w1[mt], bf.s8, zero4, 0, 0, 0);
                #pragma unroll
                for (int r = 0; r < 4; ++r) {
                    float v = fmaxf(y1t[r], 0.f);   // inactive cols contribute 0
                    as[mt][r] += v;
                    am[mt][r]  = fmaxf(am[mt][r], v);
                }
            }
        }
    }

    // ---- reduce across the 16 column-lanes ----
    #pragma unroll
    for (int mt = 0; mt < 4; ++mt) {
        #pragma unroll
        for (int r = 0; r < 4; ++r) {
            float xs = as[mt][r], xm = am[mt][r];
            xs += __shfl_xor(xs, 1, 64);  xm = fmaxf(xm, __shfl_xor(xm, 1, 64));
            xs += __shfl_xor(xs, 2, 64);  xm = fmaxf(xm, __shfl_xor(xm, 2, 64));
            xs += __shfl_xor(xs, 4, 64);  xm = fmaxf(xm, __shfl_xor(xm, 4, 64));
            xs += __shfl_xor(xs, 8, 64);  xm = fmaxf(xm, __shfl_xor(xm, 8, 64));
            as[mt][r] = xs; am[mt][r] = xm;
        }
    }

    // ---- stage channel-shuffled 192 floats, then 3 coalesced line writes ----
    float* sr = scr3[wv];
    if (c == 0) {
        #pragma unroll
        for (int mt = 0; mt < 4; ++mt)
            #pragma unroll
            for (int r = 0; r < 4; ++r) {
                const int ch = mt * 16 + g * 4 + r;
                sr[ch * 3 + 0] = as[mt][r];
                sr[ch * 3 + 1] = am[mt][r];
            }
    }
    sr[lane * 3 + 2] = mpl;
    __builtin_amdgcn_wave_barrier();
    asm volatile("s_waitcnt lgkmcnt(0)" ::: "memory");
    __builtin_amdgcn_sched_barrier(0);

    float* o = out + (size_t)seg * 192;
    #pragma unroll
    for (int p = 0; p < 3; ++p)
        o[p * 64 + lane] = sr[p * 64 + lane];
}

extern "C" void kernel_launch(void* const* d_in, const int* in_sizes, int n_in,
                              void* d_out, int out_size, void* d_ws, size_t ws_size,
                              hipStream_t stream)
{
    const float* inputs = (const float*)d_in[0];
    const int*   unq    = (const int*)d_in[1];
    const float* W1  = (const float*)d_in[3];
    const float* g1  = (const float*)d_in[4];
    const float* b1  = (const float*)d_in[5];
    const float* m1  = (const float*)d_in[6];
    const float* v1  = (const float*)d_in[7];
    const float* W2a = (const float*)d_in[8];
    const float* g2a = (const float*)d_in[9];
    const float* b2a = (const float*)d_in[10];
    const float* m2a = (const float*)d_in[11];
    const float* v2a = (const float*)d_in[12];
    const float* W2b = (const float*)d_in[13];
    const float* g2b = (const float*)d_in[14];
    const float* b2b = (const float*)d_in[15];
    const float* m2b = (const float*)d_in[16];
    const float* v2b = (const float*)d_in[17];

    float* wsf = (float*)d_ws;
    float* out = (float*)d_out;
    const int N = in_sizes[0] / 16;
    const int S = out_size / 192;

    float* mpp  = wsf + OFF_MPP;
    float* mpf  = wsf + OFF_MPF;
    int*   cnt  = (int*)(wsf + OFF_CNT);
    int*   offs = (int*)(wsf + OFF_OFFS);
    int*   cur  = (int*)(wsf + OFF_CUR);
    uint4* inpS = (uint4*)(wsf + OFF_INPS);

    // zero mpp + mpf + cnt (contiguous region)
    hipMemsetAsync(mpp, 0, (size_t)(OFF_CNT + 20016 - OFF_MPP) * sizeof(float), stream);

    init_k<<<1 + (N + 255) / 256, 256, 0, stream>>>(
        W1, g1, b1, m1, v1, W2a, g2a, b2a, m2a, v2a, W2b, g2b, b2b, m2b, v2b,
        (unsigned short*)d_ws, wsf, unq, cnt, N);

    scan_k<<<1, 1024, 0, stream>>>(cnt, offs, cur, S);

    scatbr2_k<<<(N + 255) / 256, 256, 0, stream>>>(inputs, unq, cur, inpS,
                                                   (const uint4*)d_ws, wsf, mpp, N);

    fin_k<<<1, 64, 0, stream>>>(mpp, mpf);

    seg1_k<<<(S + 3) / 4, 256, 0, stream>>>(inpS, offs, (const uint4*)d_ws,
                                            mpf, out, S);
}